// Round 3
// baseline (316.024 us; speedup 1.0000x reference)
//
#include <hip/hip_runtime.h>
#include <math.h>

#define BB 8
#define MI 16
#define NN 409600          // 640*640
#define CEPS 1e-12f
#define GPB 100            // blocks per image; each handles 4 contiguous 1024-px chunks
#define TPB 256

// ws float layout — NO zero-init required anywhere (every slot written before read):
//   PS:  k_sums partials [b][v][blk], v<80 (v=c*16+m sums for c<4; v=64+m counts)
//   G:   [b][m][4]  (float4 aligned)
//   VAL: [b][m]
//   PP:  k_pull partials [b][v][blk], v<32 (v=m loss sums; v=16+m counts)
#define WS_PS   0
#define WS_G    (BB*80*GPB)            // 64000
#define WS_VAL  (WS_G + BB*MI*4)       // 64512
#define WS_PP   (WS_VAL + BB*MI)       // 64640

// pick value v (= c*16+m) from the four unrolled register arrays; v is a
// compile-time constant after full unroll so this folds to a register ref
#define VALK(v) ((v) < 16 ? a0[(v) & 15] : (v) < 32 ? a1[(v) & 15] \
               : (v) < 48 ? a2[(v) & 15] : a3[(v) & 15])

__global__ __launch_bounds__(TPB) void k_sums(
    const float* __restrict__ outputs, const int* __restrict__ gt_kernels,
    float* __restrict__ ws) {
  __shared__ float red[TPB * 36];      // pad 36 floats/row
  __shared__ float cw[4 * MI];         // per-wave counts
  __shared__ float outbuf[80];
  const int b = blockIdx.y, blk = blockIdx.x, tid = threadIdx.x;

  float a0[MI], a1[MI], a2[MI], a3[MI];
  unsigned int wcnt[MI];
#pragma unroll
  for (int m = 0; m < MI; m++) { a0[m] = 0.f; a1[m] = 0.f; a2[m] = 0.f; a3[m] = 0.f; wcnt[m] = 0u; }

  const float* s0 = outputs + (size_t)(b * 8 + 4) * NN;
  const int* gkb = gt_kernels + (size_t)b * NN;
  const int base = blk * 4096;

#pragma unroll
  for (int c = 0; c < 4; c++) {
    const int pix = base + c * 1024 + tid * 4;
    const int4 id4 = *(const int4*)(gkb + pix);
    const float4 x0 = *(const float4*)(s0 + pix);
    const float4 x1 = *(const float4*)(s0 + NN + pix);
    const float4 x2 = *(const float4*)(s0 + 2 * NN + pix);
    const float4 x3 = *(const float4*)(s0 + 3 * NN + pix);
#define SLOTK(IDC, XC)                                                       \
    {                                                                        \
      const int id = id4.IDC;                                                \
      _Pragma("unroll")                                                      \
      for (int m = 0; m < MI; m++) {                                         \
        const bool e = (id == m);                                            \
        wcnt[m] += (unsigned)__popcll(__ballot(e));                          \
        const float f = e ? 1.f : 0.f;                                       \
        a0[m] += f * x0.XC; a1[m] += f * x1.XC;                              \
        a2[m] += f * x2.XC; a3[m] += f * x3.XC;                              \
      }                                                                      \
    }
    SLOTK(x, x) SLOTK(y, y) SLOTK(z, z) SLOTK(w, w)
#undef SLOTK
  }

  // per-wave counts (wave-uniform) -> LDS, lane 0 only
  if ((tid & 63) == 0) {
    const int w = tid >> 6;
#pragma unroll
    for (int m = 0; m < MI; m++) cw[w * MI + m] = (float)wcnt[m];
  }

  // block-reduce the 64 float sums in 2 rounds of 32 values
#pragma unroll
  for (int r = 0; r < 2; r++) {
    __syncthreads();
#pragma unroll
    for (int j = 0; j < 32; j++) red[tid * 36 + j] = VALK(r * 32 + j);
    __syncthreads();
    const int m = tid & 31, grp = tid >> 5;   // 8 groups of 32 rows
    float p = 0.f;
#pragma unroll
    for (int k = 0; k < 32; k++) p += red[(grp * 32 + k) * 36 + m];
    __syncthreads();
    red[grp * 36 + m] = p;
    __syncthreads();
    if (tid < 32) {
      float t = 0.f;
#pragma unroll
      for (int g = 0; g < 8; g++) t += red[g * 36 + tid];
      outbuf[r * 32 + tid] = t;
    }
  }
  __syncthreads();
  if (tid < MI)
    outbuf[64 + tid] = cw[tid] + cw[MI + tid] + cw[2 * MI + tid] + cw[3 * MI + tid];
  __syncthreads();
  if (tid < 80) ws[WS_PS + (b * 80 + tid) * GPB + blk] = outbuf[tid];
}

__global__ void k_finG(float* __restrict__ ws) {
  __shared__ float part[4 * 80];
  __shared__ float tot[80];
  const int b = blockIdx.x, t = threadIdx.x;   // 320 threads
  const int v = t % 80, h = t / 80;            // h < 4
  float s = 0.f;
  const float* src = ws + WS_PS + (b * 80 + v) * GPB + h * 25;
#pragma unroll 5
  for (int k = 0; k < 25; k++) s += src[k];
  part[h * 80 + v] = s;
  __syncthreads();
  if (t < 80) tot[t] = part[t] + part[80 + t] + part[160 + t] + part[240 + t];
  __syncthreads();
  if (t < MI) {
    const float cnt = tot[64 + t];
    const float inv = 1.f / fmaxf(cnt, 1.f);
    float4 g;
    g.x = tot[0 * 16 + t] * inv;
    g.y = tot[1 * 16 + t] * inv;
    g.z = tot[2 * 16 + t] * inv;
    g.w = tot[3 * 16 + t] * inv;
    ((float4*)(ws + WS_G))[b * MI + t] = g;
    ws[WS_VAL + b * MI + t] = (cnt > 0.f && t >= 1) ? 1.f : 0.f;
  }
}

__global__ __launch_bounds__(TPB) void k_pull(
    const float* __restrict__ outputs, const int* __restrict__ gt_texts,
    float* __restrict__ ws) {
  __shared__ float red[TPB * 20];
  __shared__ float cw[4 * MI];
  __shared__ float outbuf[32];
  __shared__ float4 sG[MI];
  const int b = blockIdx.y, blk = blockIdx.x, tid = threadIdx.x;
  if (tid < MI) sG[tid] = ((const float4*)(ws + WS_G))[b * MI + tid];
  __syncthreads();

  float al[MI];
  unsigned int wcnt[MI];
#pragma unroll
  for (int m = 0; m < MI; m++) { al[m] = 0.f; wcnt[m] = 0u; }

  const float* s0 = outputs + (size_t)(b * 8 + 4) * NN;
  const int* ttb = gt_texts + (size_t)b * NN;
  const int base = blk * 4096;

#pragma unroll
  for (int c = 0; c < 4; c++) {
    const int pix = base + c * 1024 + tid * 4;
    const int4 id4 = *(const int4*)(ttb + pix);
    const float4 x0 = *(const float4*)(s0 + pix);
    const float4 x1 = *(const float4*)(s0 + NN + pix);
    const float4 x2 = *(const float4*)(s0 + 2 * NN + pix);
    const float4 x3 = *(const float4*)(s0 + 3 * NN + pix);
#define SLOTP(IDC, XC)                                                       \
    {                                                                        \
      const int id = id4.IDC;                                                \
      const float4 g = sG[id];                                               \
      const float d0 = x0.XC - g.x, d1 = x1.XC - g.y;                        \
      const float d2 = x2.XC - g.z, d3 = x3.XC - g.w;                        \
      const float dist = sqrtf(d0*d0 + d1*d1 + d2*d2 + d3*d3 + CEPS) - 0.5f; \
      const float dm = fmaxf(dist, 0.f);                                     \
      const float l = log1pf(dm * dm);                                       \
      _Pragma("unroll")                                                      \
      for (int m = 0; m < MI; m++) {                                         \
        const bool e = (id == m);                                            \
        wcnt[m] += (unsigned)__popcll(__ballot(e));                          \
        al[m] += (e ? 1.f : 0.f) * l;                                        \
      }                                                                      \
    }
    SLOTP(x, x) SLOTP(y, y) SLOTP(z, z) SLOTP(w, w)
#undef SLOTP
  }

  if ((tid & 63) == 0) {
    const int w = tid >> 6;
#pragma unroll
    for (int m = 0; m < MI; m++) cw[w * MI + m] = (float)wcnt[m];
  }

  // block-reduce the 16 loss sums
  __syncthreads();
#pragma unroll
  for (int j = 0; j < MI; j++) red[tid * 20 + j] = al[j];
  __syncthreads();
  const int m = tid & 15, grp = tid >> 4;   // 16 groups of 16 rows
  float p = 0.f;
#pragma unroll
  for (int k = 0; k < 16; k++) p += red[(grp * 16 + k) * 20 + m];
  __syncthreads();
  red[grp * 20 + m] = p;
  __syncthreads();
  if (tid < MI) {
    float t = 0.f;
#pragma unroll
    for (int g = 0; g < 16; g++) t += red[g * 20 + tid];
    outbuf[tid] = t;
    outbuf[MI + tid] = cw[tid] + cw[MI + tid] + cw[2 * MI + tid] + cw[3 * MI + tid];
  }
  __syncthreads();
  if (tid < 32) ws[WS_PP + (b * 32 + tid) * GPB + blk] = outbuf[tid];
}

__global__ void k_final(const float* __restrict__ ws, float* __restrict__ out) {
  __shared__ float tot[256];                  // [b][v], v<32
  const int t = threadIdx.x;                  // 256 threads
  const int b = t >> 5, v = t & 31;
  float s = 0.f;
  const float* src = ws + WS_PP + (b * 32 + v) * GPB;
#pragma unroll 4
  for (int k = 0; k < GPB; k++) s += src[k];
  tot[t] = s;
  __syncthreads();
  if (t < BB) {
    const int bb = t;
    const float* G = ws + WS_G;
    const float* valid = ws + WS_VAL;
    float nv = 0.f;
    for (int m = 0; m < MI; m++) nv += valid[bb * MI + m];
    float pull = 0.f;
    for (int m = 0; m < MI; m++) {
      const float per = tot[bb * 32 + m] / fmaxf(tot[bb * 32 + 16 + m], 1.f);
      pull += per * valid[bb * MI + m];
    }
    pull /= fmaxf(nv, 1.f);
    float push = 0.f;
    for (int i = 0; i < MI; i++) {
      if (valid[bb * MI + i] == 0.f) continue;
      for (int j = i + 1; j < MI; j++) {
        if (valid[bb * MI + j] == 0.f) continue;
        float d2 = CEPS;
        for (int c = 0; c < 4; c++) {
          const float df = G[(bb * MI + i) * 4 + c] - G[(bb * MI + j) * 4 + c];
          d2 += df * df;
        }
        const float dk = sqrtf(d2);
        const float tt = fmaxf(3.f - dk, 0.f);
        push += log1pf(tt * tt);
      }
    }
    const float denom = nv * (nv - 1.f);
    push = (nv > 1.f) ? push / fmaxf(denom, 1.f) : 0.f;
    out[bb] = pull;
    out[BB + bb] = push;
  }
}

extern "C" void kernel_launch(void* const* d_in, const int* in_sizes, int n_in,
                              void* d_out, int out_size, void* d_ws, size_t ws_size,
                              hipStream_t stream) {
  const float* outputs = (const float*)d_in[0];
  const int* gt_texts = (const int*)d_in[1];
  const int* gt_kernels = (const int*)d_in[2];
  float* ws = (float*)d_ws;
  float* out = (float*)d_out;

  dim3 grid(GPB, BB);
  k_sums<<<grid, TPB, 0, stream>>>(outputs, gt_kernels, ws);
  k_finG<<<BB, 320, 0, stream>>>(ws);
  k_pull<<<grid, TPB, 0, stream>>>(outputs, gt_texts, ws);
  k_final<<<1, 256, 0, stream>>>(ws, out);
}